// Round 1
// 576.461 us; speedup vs baseline: 1.0770x; 1.0770x over previous
//
#include <hip/hip_runtime.h>
#include <math.h>

// Problem constants (from reference): B,H,U,C,K = 256,1024,1024,512,10
#define BB 256
#define HH 1024
#define UU 1024
#define CC 512
#define KK 10

// fp32 expf(-x) is exactly 0 (or a <1e-45 subnormal) for x > ~104.
// Contributions with beta*(kappa-u)^2 > 110 are identically zero in the
// fp32 reference itself — skipping them is EXACT, not approximate.
#define EXP_CUTOFF 110.0f

__device__ __forceinline__ float softplus_f(float x) {
    return fmaxf(x, 0.0f) + log1pf(expf(-fabsf(x)));
}

// Fully fused: one block per batch row b, 256 threads (4 waves).
//  1. params[30] = h[b] @ W.T + bias   (float4 loads, 8 rows interleaved/wave)
//  2. alpha/beta/kappa + active-u bound (t < K)
//  3. phi[b, 0:U]                       (exp underflow zeroes the tail)
//  4. window[b,:] = sum_{u<u_hi} phi*c_seq  (float4, u split across 2 halves)
__global__ __launch_bounds__(256, 1)
void softwindow_fused(const float* __restrict__ h,
                      const float* __restrict__ c_seq,
                      const float* __restrict__ k_prev,
                      const float* __restrict__ W,
                      const float* __restrict__ bias,
                      float* __restrict__ window,
                      float* __restrict__ phi_out,
                      float* __restrict__ kappa_out) {
    __shared__ float sh[HH];          // h row
    __shared__ float sphi[UU];        // phi row
    __shared__ float sparams[3 * KK];
    __shared__ float sa[KK], sb[KK], sk[KK];
    __shared__ float sbound[KK];
    __shared__ int s_hi;
    __shared__ float4 spart[CC / 4];  // cross-half combine for window

    const int b = blockIdx.x;
    const int t = threadIdx.x;        // 0..255

    // ---- 1. stage h row (1024 floats = 256 float4) ----
    ((float4*)sh)[t] = ((const float4*)(h + (size_t)b * HH))[t];
    __syncthreads();

    const int wave = t >> 6;
    const int lane = t & 63;
    const int j0 = wave * 8;          // waves 0..2: rows j0..j0+7; wave 3: 24..29

    // 8 row-sums per lane, statically indexed (no scratch), 32 independent
    // float4 W loads in flight per lane -> latency fully hidden at 1 wave/SIMD.
    float sums[8];
    #pragma unroll
    for (int r = 0; r < 8; ++r) sums[r] = 0.0f;

    const float4* sh4 = (const float4*)sh;
    #pragma unroll
    for (int i = 0; i < HH / 256; ++i) {          // 4 iterations
        const float4 hv = sh4[lane + 64 * i];
        #pragma unroll
        for (int r = 0; r < 8; ++r) {
            int jj = j0 + r;
            if (jj > 3 * KK - 1) jj = 3 * KK - 1; // clamp: wave 3 rows 30,31 -> 29 (discarded)
            const float4 wv = ((const float4*)(W + (size_t)jj * HH))[lane + 64 * i];
            sums[r] = fmaf(hv.x, wv.x, sums[r]);
            sums[r] = fmaf(hv.y, wv.y, sums[r]);
            sums[r] = fmaf(hv.z, wv.z, sums[r]);
            sums[r] = fmaf(hv.w, wv.w, sums[r]);
        }
    }
    #pragma unroll
    for (int r = 0; r < 8; ++r) {
        float s = sums[r];
        #pragma unroll
        for (int off = 32; off > 0; off >>= 1) s += __shfl_down(s, off);
        const int jj = j0 + r;
        if (lane == 0 && jj < 3 * KK) sparams[jj] = s + bias[jj];
    }
    __syncthreads();

    // ---- 2. activations + active-u bound ----
    if (t < KK) {
        float a  = softplus_f(sparams[t]) + 1e-4f;
        float be = fminf(fmaxf(softplus_f(sparams[KK + t]), 0.1f), 10.0f);
        float ka = k_prev[b * KK + t] + softplus_f(sparams[2 * KK + t]) * 0.1f;
        sa[t] = a;
        sb[t] = be;
        sk[t] = ka;
        kappa_out[b * KK + t] = ka;                  // third output
        sbound[t] = ka + sqrtf(EXP_CUTOFF / be);     // beyond this u: exp == 0 in fp32
    }
    __syncthreads();
    if (t == 0) {
        float mb = sbound[0];
        #pragma unroll
        for (int k = 1; k < KK; ++k) mb = fmaxf(mb, sbound[k]);
        int hi = (mb < 0.0f) ? 0 : (int)ceilf(mb) + 1;
        s_hi = hi > UU ? UU : hi;
    }
    __syncthreads();

    // ---- 3. phi for all u (4 per thread), second output ----
    #pragma unroll
    for (int i = 0; i < UU / 256; ++i) {
        const int u = t + i * 256;
        const float uf = (float)u;
        float p = 0.0f;
        #pragma unroll
        for (int k = 0; k < KK; ++k) {
            const float d = sk[k] - uf;
            p += sa[k] * __expf(-sb[k] * d * d);
        }
        sphi[u] = p;
        phi_out[(size_t)b * UU + u] = p;
    }
    __syncthreads();

    // ---- 4. window over the active u range only (float4, two u-halves) ----
    const int hi = s_hi;
    const int col  = t & 127;         // float4 column 0..127  (CC/4 = 128)
    const int half = t >> 7;          // waves 0,1 -> even u; waves 2,3 -> odd u
    const float4* base4 = (const float4*)(c_seq + (size_t)b * UU * CC);
    float4 acc = {0.0f, 0.0f, 0.0f, 0.0f};
    #pragma unroll 4
    for (int u = half; u < hi; u += 2) {
        const float p = sphi[u];
        const float4 v = base4[(size_t)u * (CC / 4) + col];
        acc.x = fmaf(p, v.x, acc.x);
        acc.y = fmaf(p, v.y, acc.y);
        acc.z = fmaf(p, v.z, acc.z);
        acc.w = fmaf(p, v.w, acc.w);
    }
    if (half) spart[col] = acc;
    __syncthreads();
    if (!half) {
        const float4 o = spart[col];
        acc.x += o.x; acc.y += o.y; acc.z += o.z; acc.w += o.w;
        ((float4*)(window + (size_t)b * CC))[col] = acc;
    }
}

extern "C" void kernel_launch(void* const* d_in, const int* in_sizes, int n_in,
                              void* d_out, int out_size, void* d_ws, size_t ws_size,
                              hipStream_t stream) {
    const float* h      = (const float*)d_in[0];   // [B,H]
    const float* c_seq  = (const float*)d_in[1];   // [B,U,C]
    const float* k_prev = (const float*)d_in[2];   // [B,K]
    const float* W      = (const float*)d_in[3];   // [3K,H]
    const float* bias   = (const float*)d_in[4];   // [3K]

    float* out     = (float*)d_out;
    float* window  = out;                          // [B,C]
    float* phi     = out + BB * CC;                // [B,U]
    float* kappa_o = out + BB * CC + BB * UU;      // [B,K]

    softwindow_fused<<<BB, 256, 0, stream>>>(h, c_seq, k_prev, W, bias,
                                             window, phi, kappa_o);
}